// Round 1
// baseline (190.792 us; speedup 1.0000x reference)
//
#include <hip/hip_runtime.h>

#ifndef N_NODES
#define N_NODES 100000
#endif
#define E_EDGES 2000000
#define CIN 16
// HUMAN_EXHALATION_FLOW = 0.0001 * 40000 = 4.0
#define EXH_FLOW 4.0f

// origin_data layout: (N, T=8, 3) f32; last timestep fields at n*24 + {21,22,23}
// = {concentration, people, size}

__global__ void init_nodes_kernel(const float* __restrict__ origin,
                                  float* __restrict__ out,
                                  int* __restrict__ max_ord) {
    int n = blockIdx.x * blockDim.x + threadIdx.x;
    if (n >= N_NODES) return;
    size_t base = (size_t)n * 24;
    float conc   = origin[base + 21];
    float people = origin[base + 22];
    float size   = origin[base + 23];
    out[n] = conc + EXH_FLOW * people / size;
    max_ord[n] = -1;
}

__global__ void edge_pass1_kernel(const float* __restrict__ x,
                                  const float* __restrict__ w,
                                  const float* __restrict__ b,
                                  const int* __restrict__ src,
                                  const int* __restrict__ dst,
                                  float* __restrict__ flow,
                                  int* __restrict__ max_ord) {
    int e = blockIdx.x * blockDim.x + threadIdx.x;
    if (e >= E_EDGES) return;
    const float4* xv = (const float4*)(x + (size_t)e * CIN);
    const float4* wv = (const float4*)w;
    float4 a0 = xv[0], a1 = xv[1], a2 = xv[2], a3 = xv[3];
    float4 w0 = wv[0], w1 = wv[1], w2 = wv[2], w3 = wv[3];
    float acc = a0.x * w0.x + a0.y * w0.y + a0.z * w0.z + a0.w * w0.w
              + a1.x * w1.x + a1.y * w1.y + a1.z * w1.z + a1.w * w1.w
              + a2.x * w2.x + a2.y * w2.y + a2.z * w2.z + a2.w * w2.w
              + a3.x * w3.x + a3.y * w3.y + a3.z * w3.z + a3.w * w3.w;
    float out = acc + b[0];
    flow[e] = out;
    int s = src[e], d = dst[e];
    if (s != d) {
        atomicMax(&max_ord[s], 2 * e);
        atomicMax(&max_ord[d], 2 * e + 1);
    }
}

__global__ void edge_pass2_kernel(const float* __restrict__ origin,
                                  const int* __restrict__ src,
                                  const int* __restrict__ dst,
                                  const float* __restrict__ flow,
                                  const int* __restrict__ max_ord,
                                  float* __restrict__ out) {
    int e = blockIdx.x * blockDim.x + threadIdx.x;
    if (e >= E_EDGES) return;
    int s = src[e], d = dst[e];
    if (s == d) return;
    bool win_s = (max_ord[s] == 2 * e);
    bool win_d = (max_ord[d] == 2 * e + 1);
    if (!win_s && !win_d) return;
    float val = flow[e];
    float conc_s = origin[(size_t)s * 24 + 21];
    if (win_s) {
        float size_s = origin[(size_t)s * 24 + 23];
        // unique winner per node -> single writer, non-atomic RMW is safe
        out[s] += val * conc_s / size_s;
    }
    if (win_d) {
        float size_d = origin[(size_t)d * 24 + 23];
        out[d] += val * conc_s / size_d;
    }
}

extern "C" void kernel_launch(void* const* d_in, const int* in_sizes, int n_in,
                              void* d_out, int out_size, void* d_ws, size_t ws_size,
                              hipStream_t stream) {
    const float* origin = (const float*)d_in[0];   // (N, 8, 3)
    const float* x      = (const float*)d_in[1];   // (E, 1, 16)
    const float* conv_w = (const float*)d_in[2];   // (1, 16, 1, 1)
    const float* conv_b = (const float*)d_in[3];   // (1,)
    const int*   eidx   = (const int*)d_in[4];     // (2, E)
    const int* src = eidx;
    const int* dst = eidx + E_EDGES;

    float* out    = (float*)d_out;        // [0, N): result; [N, N+E): flow
    float* flow   = out + N_NODES;
    int*   max_ord = (int*)d_ws;          // N ints

    const int BLK = 256;
    init_nodes_kernel<<<(N_NODES + BLK - 1) / BLK, BLK, 0, stream>>>(origin, out, max_ord);
    edge_pass1_kernel<<<(E_EDGES + BLK - 1) / BLK, BLK, 0, stream>>>(x, conv_w, conv_b,
                                                                     src, dst, flow, max_ord);
    edge_pass2_kernel<<<(E_EDGES + BLK - 1) / BLK, BLK, 0, stream>>>(origin, src, dst,
                                                                     flow, max_ord, out);
}